// Round 5
// baseline (205.171 us; speedup 1.0000x reference)
//
#include <hip/hip_runtime.h>
#include <hip/hip_bf16.h>
#include <stdint.h>

typedef __attribute__((ext_vector_type(8))) short short8;
typedef __attribute__((ext_vector_type(4))) float floatx4;
typedef __attribute__((ext_vector_type(16))) float floatx16;
typedef __attribute__((ext_vector_type(2))) long longx2;

#define DEVI __device__ __forceinline__
#define MFMA16(a, b, c) __builtin_amdgcn_mfma_f32_16x16x32_bf16((a), (b), (c), 0, 0, 0)
#define MFMA32(a, b, c) __builtin_amdgcn_mfma_f32_32x32x16_fp8_fp8((a), (b), (c), 0, 0, 0)

typedef __attribute__((address_space(3))) unsigned int lds_u32;
typedef __attribute__((address_space(1))) const unsigned int glb_u32;
// async 16B/lane DMA global->LDS: lds dest = wave-uniform base + lane*16 (contiguous 1KB/wave)
#define GLOAD_LDS16(g, l) __builtin_amdgcn_global_load_lds((glb_u32*)(g), (lds_u32*)(l), 16, 0, 0)

DEVI unsigned short f2bf(float x) {
    union { float f; unsigned int u; } v; v.f = x;
    unsigned int r = v.u + 0x7FFFu + ((v.u >> 16) & 1u);
    return (unsigned short)(r >> 16);
}
DEVI float bf2f(unsigned short h) {
    union { unsigned int u; float f; } v; v.u = ((unsigned int)h) << 16;
    return v.f;
}
DEVI unsigned char f2fp8(float x) {   // OCP e4m3 via HW converter
    int c = __builtin_amdgcn_cvt_pk_fp8_f32(x, x, 0, false);
    return (unsigned char)(c & 0xFF);
}

// ---------------- projection GEMM: x = f32_in @ Wp^T + bias (fused cast + weight transpose) ----------------

__global__ __launch_bounds__(256) void gemm_bias(
    const float* __restrict__ A,               // f32 input [16384][128]
    const float* __restrict__ Wp,              // f32 weights [128][256] (transposed in-kernel)
    const float* __restrict__ bias,
    unsigned short* __restrict__ Cb,           // bf16 out [16384][256]
    int N)
{
    __shared__ __align__(16) unsigned short As[64][136];
    __shared__ __align__(16) unsigned short Bs[64][136];
    const int tid  = threadIdx.x;
    const int w    = tid >> 6;
    const int lane = tid & 63;
    const int quad = lane >> 4;
    const int l15  = lane & 15;
    const int m0 = blockIdx.x * 64;
    const int n0 = blockIdx.y * 64;

    floatx4 acc[4];
    #pragma unroll
    for (int t = 0; t < 4; ++t) acc[t] = (floatx4)0.0f;

    // K = 128: single chunk. A staged f32 -> bf16 in-register (fused cast).
    #pragma unroll
    for (int it = 0; it < 8; ++it) {
        int idx = tid + it * 256;             // 0..2047 float4s
        int r = idx >> 5, c4 = idx & 31;
        float4 v = *(const float4*)&A[(size_t)(m0 + r) * 128 + c4 * 4];
        ushort4 o;
        o.x = f2bf(v.x); o.y = f2bf(v.y); o.z = f2bf(v.z); o.w = f2bf(v.w);
        *(ushort4*)&As[r][c4 * 4] = o;
    }
    // B staged with on-the-fly transpose+cast: Bs[n][k] = bf16(Wp[k][n0+n])
    #pragma unroll
    for (int it = 0; it < 8; ++it) {
        int flat = tid + it * 256;            // 0..2047 float4s: k = flat>>4, n4 = flat&15
        int k = flat >> 4, n4 = flat & 15;
        float4 v = *(const float4*)&Wp[(size_t)k * 256 + n0 + n4 * 4];
        Bs[n4 * 4 + 0][k] = f2bf(v.x);
        Bs[n4 * 4 + 1][k] = f2bf(v.y);
        Bs[n4 * 4 + 2][k] = f2bf(v.z);
        Bs[n4 * 4 + 3][k] = f2bf(v.w);
    }
    __syncthreads();
    #pragma unroll
    for (int s = 0; s < 4; ++s) {
        short8 a = *(const short8*)&As[w * 16 + l15][s * 32 + quad * 8];
        #pragma unroll
        for (int t = 0; t < 4; ++t) {
            short8 bfr = *(const short8*)&Bs[t * 16 + l15][s * 32 + quad * 8];
            acc[t] = MFMA16(a, bfr, acc[t]);
        }
    }

    // epilogue via LDS overlay -> coalesced 16B stores (both column halves)
    __syncthreads();
    unsigned short* T = &As[0][0];            // 64 x 80 ushort overlay (10 KB)
    #pragma unroll
    for (int t = 0; t < 4; ++t) {
        int n = n0 + t * 16 + l15;
        float bs = bias[n];
        #pragma unroll
        for (int r = 0; r < 4; ++r)
            T[(w * 16 + quad * 4 + r) * 80 + t * 16 + l15] = f2bf(acc[t][r] + bs);
    }
    __syncthreads();
    int row = tid >> 2, c8 = (tid & 3) * 8;
    #pragma unroll
    for (int half = 0; half < 2; ++half) {
        int4 ov = *(const int4*)&T[row * 80 + c8 + half * 32];
        *(int4*)&Cb[(size_t)(m0 + row) * N + n0 + c8 + half * 32] = ov;
    }
}

// ---------------- fused Q/K/V GEMM: fp8 + fragment-packed output, in-kernel weight transpose ----------------
// blockIdx.z selects weight/bias/output. Q written row-major fp8; K and V written DIRECTLY
// in the 32x32x16 slice-paired fragment layout flash_attn consumes. All global stores
// 16B/thread via a 5 KB LDS tile-transpose overlaid on As.
//
// Packed layouts (per batch, 1 MB, tile kt = key>>5, 8 KB/tile):
//  K: byte j at kt*8192 + (s>>1)*1024 + lane*16 + (s&1)*8  = K[kt*32+(lane&31)][s*16+(lane>>5)*8+j]
//  V: byte j at kt*8192 + fb*1024    + lane*16 + s2*8      = V[kt*32+s2*16+(lane>>5)*8+j][fb*32+(lane&31)]

__global__ __launch_bounds__(256) void gemm_qkv(
    const unsigned short* __restrict__ A,
    const float* __restrict__ W0, const float* __restrict__ W1, const float* __restrict__ W2,
    const float* __restrict__ b0, const float* __restrict__ b1, const float* __restrict__ b2,
    unsigned char* __restrict__ C0, unsigned char* __restrict__ C1, unsigned char* __restrict__ C2,
    int N)
{
    const float* W    = (blockIdx.z == 0) ? W0 : (blockIdx.z == 1) ? W1 : W2;
    const float* bias = (blockIdx.z == 0) ? b0 : (blockIdx.z == 1) ? b1 : b2;
    unsigned char* Cb = (blockIdx.z == 0) ? C0 : (blockIdx.z == 1) ? C1 : C2;

    __shared__ __align__(16) unsigned short As[64][136];
    __shared__ __align__(16) unsigned short Bs[64][136];
    const int tid  = threadIdx.x;
    const int w    = tid >> 6;
    const int lane = tid & 63;
    const int quad = lane >> 4;
    const int l15  = lane & 15;
    const int m0 = blockIdx.x * 64;
    const int n0 = blockIdx.y * 64;

    floatx4 acc[4];
    #pragma unroll
    for (int t = 0; t < 4; ++t) acc[t] = (floatx4)0.0f;

    for (int kc = 0; kc < 256; kc += 128) {
        __syncthreads();
        #pragma unroll
        for (int idx = tid; idx < 1024; idx += 256) {
            int r = idx >> 4, g = idx & 15;
            *(short8*)&As[r][g * 8] = *(const short8*)&A[(size_t)(m0 + r) * 256 + kc + g * 8];
        }
        // B: transpose+cast from W f32 [256][256]: Bs[n][k] = bf16(W[kc+k][n0+n])
        #pragma unroll
        for (int it = 0; it < 8; ++it) {
            int flat = tid + it * 256;        // k = flat>>4 (0..127), n4 = flat&15
            int k = flat >> 4, n4 = flat & 15;
            float4 v = *(const float4*)&W[(size_t)(kc + k) * 256 + n0 + n4 * 4];
            Bs[n4 * 4 + 0][k] = f2bf(v.x);
            Bs[n4 * 4 + 1][k] = f2bf(v.y);
            Bs[n4 * 4 + 2][k] = f2bf(v.z);
            Bs[n4 * 4 + 3][k] = f2bf(v.w);
        }
        __syncthreads();
        #pragma unroll
        for (int s = 0; s < 4; ++s) {
            short8 a = *(const short8*)&As[w * 16 + l15][s * 32 + quad * 8];
            #pragma unroll
            for (int t = 0; t < 4; ++t) {
                short8 bfr = *(const short8*)&Bs[t * 16 + l15][s * 32 + quad * 8];
                acc[t] = MFMA16(a, bfr, acc[t]);
            }
        }
    }

    // ---- epilogue: acc -> fp8 LDS tile (64x80 overlay on As) -> layout-specific stores ----
    __syncthreads();
    unsigned char* T = (unsigned char*)&As[0][0];
    #pragma unroll
    for (int t = 0; t < 4; ++t) {
        int n = n0 + t * 16 + l15;
        float bs = bias[n];
        #pragma unroll
        for (int r = 0; r < 4; ++r)
            T[(w * 16 + quad * 4 + r) * 80 + t * 16 + l15] = f2fp8(acc[t][r] + bs);
    }
    __syncthreads();

    const int b  = m0 >> 12;             // batch (4096 keys each)
    const int mt = (m0 & 4095) >> 5;     // base 32-key tile within batch

    if (blockIdx.z == 0) {
        // Q row-major: 4 thr x 16B = full 64B row, coalesced dwordx4
        int row = tid >> 2, c16 = (tid & 3) * 16;
        int4 vq = *(const int4*)&T[row * 80 + c16];
        *(int4*)&Cb[(size_t)(m0 + row) * 256 + n0 + c16] = vq;
    } else {
        const int kt  = tid >> 7;          // 0..1 : 32-key tile within block
        const int sub = (tid >> 6) & 1;    // K: slice-pair | V: local f-block
        const int ln  = tid & 63;
        const int l31b = ln & 31, hib = ln >> 5;
        union { long h[2]; int4 v; unsigned char bts[16]; } o;
        if (blockIdx.z == 1) {
            #pragma unroll
            for (int h = 0; h < 2; ++h)
                o.h[h] = *(const long*)&T[(kt * 32 + l31b) * 80 + (sub * 2 + h) * 16 + hib * 8];
        } else {
            #pragma unroll
            for (int s2 = 0; s2 < 2; ++s2)
                #pragma unroll
                for (int j = 0; j < 8; ++j)
                    o.bts[s2 * 8 + j] = T[(kt * 32 + s2 * 16 + hib * 8 + j) * 80 + sub * 32 + l31b];
        }
        unsigned char* dst = Cb + (size_t)b * 1048576 + (size_t)(mt + kt) * 8192
                           + (size_t)((n0 >> 5) + sub) * 1024 + ln * 16;
        *(int4*)dst = o.v;
    }
}

// ---------------- flash attention v12: 4-phase fine interleave ----------------
// v11 model: per CU per iter = 2500 cyc MFMA vs 7000 wall; the loss is the chip-wide phase
// convoy (all waves burst DMA-issue, then all ds_read, then all MFMA...). v12 breaks each
// 32-key iteration into 4 phases, each {ds_read half-tile ... stage half of t+1 -> s_barrier ->
// MFMA cluster (setprio) -> s_barrier}: MFMA issue is fire-and-forget, so each phase's
// loads/VALU overlap the previous phase's in-flight MFMA backlog (T3 interleave + T5).
// Correctness barrier is still ONLY the iter-top __syncthreads (drains exactly stage(t)'s
// 8 DMAs/wave; staging targets buf^1 which all waves finished reading one full iteration
// earlier). Phase s_barriers are uniform across all 512 threads -> no deadlock.

__global__ __launch_bounds__(512, 2) void flash_attn(
    const unsigned char* __restrict__ qg,      // fp8 Q row-major [b][n][256]
    const unsigned char* __restrict__ kp,      // fragment-packed fp8 K (slice-paired)
    const unsigned char* __restrict__ vp,      // fragment-packed fp8 V (slice-paired)
    const unsigned short* __restrict__ xb,     // bf16 x for residual
    const float* __restrict__ gamma,
    float* __restrict__ out)
{
    __shared__ __align__(16) unsigned char KV[2][65536]; // [buf][kq: K 8K, V 8K]
    // merge overlay after the K-loop: Mb 64 x 264 f32 (67,584 B) + Ml 64 f32 (<= 131,072)
    float* MbF = (float*)&KV[0][0];
    float* Ml  = MbF + 64 * 264;

    const int tid  = threadIdx.x;
    const int w    = tid >> 6;
    const int lane = tid & 63;
    const int l31  = lane & 31;
    const int hi   = lane >> 5;
    const int kq   = w & 3;         // key quarter 0..3
    const int rw   = w >> 2;        // query group 0..1
    const int blk  = blockIdx.x;
    const int b    = (blk & 7) >> 1;              // XCD-pinned batch
    const int rt   = (blk >> 3) * 2 + (blk & 1);  // row-tile 0..63 (64 queries each)
    const int row0 = rt * 64 + rw * 32;

    // Q fragments (B-operand of swapped QK: col = l&31 = query, k = hi*8+j), 8 B/lane
    const size_t baseQ = ((size_t)b * 4096 + row0 + l31) * 256 + hi * 8;
    long qf[16];
    #pragma unroll
    for (int s = 0; s < 16; ++s)
        qf[s] = *(const long*)&qg[baseQ + s * 16];

    const long ones8 = 0x3838383838383838L;    // e4m3 1.0 x8

    floatx16 ctx[8];
    #pragma unroll
    for (int i = 0; i < 8; ++i) ctx[i] = (floatx16)0.0f;
    floatx16 lacc = (floatx16)0.0f;

    const unsigned char* kb_b = kp + (size_t)b * 1048576;
    const unsigned char* vb_b = vp + (size_t)b * 1048576;

    // stage half PH (p = PH*4 .. PH*4+3) of tile T into BUF; wave w owns chunks c = p*8+w.
    // chunk map: c>>4 = key-quarter, (c>>3)&1 = K/V, (c&7)*1024 = offset in the 8 KB half.
#define FA_STAGE_H(T, BUF, PH)                                                       \
    {                                                                                \
        _Pragma("unroll")                                                            \
        for (int p = (PH) * 4; p < (PH) * 4 + 4; ++p) {                              \
            const int c    = p * 8 + w;                                              \
            const int ckq  = c >> 4;                                                 \
            const int csel = (c >> 3) & 1;                                           \
            const int coff = (c & 7) * 1024;                                         \
            const unsigned char* src = (csel ? vb_b : kb_b)                          \
                + (size_t)ckq * 262144 + (size_t)(T) * 8192 + coff + lane * 16;      \
            GLOAD_LDS16(src, &KV[BUF][ckq * 16384 + csel * 8192 + coff]);            \
        }                                                                            \
    }
#define PHASE_BAR asm volatile("s_barrier" ::: "memory")

    FA_STAGE_H(0, 0, 0) FA_STAGE_H(0, 0, 1)   // prologue: full tile 0

    for (int t = 0; t < 32; ++t) {
        const int buf = t & 1;
        __syncthreads();                 // drains stage(t) (only outstanding VMEM) & makes it visible

        const unsigned char* kc = &KV[buf][kq * 16384];
        const unsigned char* vc = kc + 8192;

        floatx16 sa = (floatx16)0.0f, sb = (floatx16)0.0f;

        // ---- phase 0: K half 0 + stage half 0 of t+1 | 8 QK MFMA ----
        longx2 k0[4];
        #pragma unroll
        for (int p = 0; p < 4; ++p) k0[p] = *(const longx2*)&kc[p * 1024 + lane * 16];
        if (t < 31) FA_STAGE_H(t + 1, buf ^ 1, 0)
        PHASE_BAR;
        __builtin_amdgcn_s_setprio(1);
        #pragma unroll
        for (int p = 0; p < 4; ++p) {
            sa = MFMA32(k0[p].x, qf[2 * p],     sa);
            sb = MFMA32(k0[p].y, qf[2 * p + 1], sb);
        }
        __builtin_amdgcn_s_setprio(0);
        PHASE_BAR;

        // ---- phase 1: K half 1 + stage half 1 of t+1 | 8 QK MFMA ----
        longx2 k1[4];
        #pragma unroll
        for (int p = 0; p < 4; ++p) k1[p] = *(const longx2*)&kc[(4 + p) * 1024 + lane * 16];
        if (t < 31) FA_STAGE_H(t + 1, buf ^ 1, 1)
        PHASE_BAR;
        __builtin_amdgcn_s_setprio(1);
        #pragma unroll
        for (int p = 0; p < 4; ++p) {
            sa = MFMA32(k1[p].x, qf[2 * (4 + p)],     sa);
            sb = MFMA32(k1[p].y, qf[2 * (4 + p) + 1], sb);
        }
        __builtin_amdgcn_s_setprio(0);
        PHASE_BAR;

        // ---- phase 2: softmax (VALU) + V half 0 | 10 PV MFMA ----
        longx2 v0[4];
        #pragma unroll
        for (int p = 0; p < 4; ++p) v0[p] = *(const longx2*)&vc[p * 1024 + lane * 16];
        float e[16];
        #pragma unroll
        for (int r = 0; r < 16; ++r) e[r] = __expf(sa[r] + sb[r]);
        int X0 = __builtin_amdgcn_cvt_pk_fp8_f32(e[0],  e[1],  0,  false);
        X0     = __builtin_amdgcn_cvt_pk_fp8_f32(e[2],  e[3],  X0, true);
        int Y0 = __builtin_amdgcn_cvt_pk_fp8_f32(e[4],  e[5],  0,  false);
        Y0     = __builtin_amdgcn_cvt_pk_fp8_f32(e[6],  e[7],  Y0, true);
        int X1 = __builtin_amdgcn_cvt_pk_fp8_f32(e[8],  e[9],  0,  false);
        X1     = __builtin_amdgcn_cvt_pk_fp8_f32(e[10], e[11], X1, true);
        int Y1 = __builtin_amdgcn_cvt_pk_fp8_f32(e[12], e[13], 0,  false);
        Y1     = __builtin_amdgcn_cvt_pk_fp8_f32(e[14], e[15], Y1, true);
        asm volatile("v_permlane32_swap_b32 %0, %1" : "+v"(X0), "+v"(Y0));
        asm volatile("v_permlane32_swap_b32 %0, %1" : "+v"(X1), "+v"(Y1));
        union { int i2[2]; long l; } u0, u1;
        u0.i2[0] = X0; u0.i2[1] = Y0;
        u1.i2[0] = X1; u1.i2[1] = Y1;
        const long ap0 = u0.l;           // P[query = l&31][keys hi*8..+7 of slice 0]
        const long ap1 = u1.l;           // slice 1 (keys 16..31)
        PHASE_BAR;
        __builtin_amdgcn_s_setprio(1);
        lacc = MFMA32(ap0, ones8, lacc);
        lacc = MFMA32(ap1, ones8, lacc);
        #pragma unroll
        for (int p = 0; p < 4; ++p) {
            ctx[p] = MFMA32(ap0, v0[p].x, ctx[p]);
            ctx[p] = MFMA32(ap1, v0[p].y, ctx[p]);
        }
        __builtin_amdgcn_s_setprio(0);
        PHASE_BAR;

        // ---- phase 3: V half 1 | 8 PV MFMA ----
        longx2 v1[4];
        #pragma unroll
        for (int p = 0; p < 4; ++p) v1[p] = *(const longx2*)&vc[(4 + p) * 1024 + lane * 16];
        PHASE_BAR;
        __builtin_amdgcn_s_setprio(1);
        #pragma unroll
        for (int p = 0; p < 4; ++p) {
            ctx[4 + p] = MFMA32(ap0, v1[p].x, ctx[4 + p]);
            ctx[4 + p] = MFMA32(ap1, v1[p].y, ctx[4 + p]);
        }
        __builtin_amdgcn_s_setprio(0);
        // iter-top __syncthreads follows
    }
#undef FA_STAGE_H
#undef PHASE_BAR

    // ---- merge the 4 key-quarters (plain sums; maxless softmax is linear) ----
    __syncthreads();
    for (int pass = 3; pass >= 0; --pass) {
        if (kq == pass) {
            #pragma unroll
            for (int fb = 0; fb < 8; ++fb) {
                #pragma unroll
                for (int r = 0; r < 16; ++r) {
                    int row = rw * 32 + (r & 3) + 8 * (r >> 2) + 4 * hi;
                    int idx = row * 264 + fb * 32 + l31;
                    float prev = (pass == 3) ? 0.0f : MbF[idx];
                    MbF[idx] = prev + ctx[fb][r];
                }
            }
            if (l31 == 0) {
                #pragma unroll
                for (int r = 0; r < 16; ++r) {
                    int row = rw * 32 + (r & 3) + 8 * (r >> 2) + 4 * hi;
                    float prev = (pass == 3) ? 0.0f : Ml[row];
                    Ml[row] = prev + lacc[r];
                }
            }
        }
        __syncthreads();
    }

    // ---- cooperative epilogue: out = gamma * Mb / Ml + x (coalesced float4) ----
    const float g = gamma[0];
    const int row = tid >> 3;          // 0..63
    const int c0  = (tid & 7) * 32;    // 0..224
    const float rl = 1.0f / Ml[row];
    const size_t o = ((size_t)b * 4096 + rt * 64 + row) * 256 + c0;
    #pragma unroll
    for (int j = 0; j < 4; ++j) {
        short8 xv = *(const short8*)&xb[o + j * 8];
        float res[8];
        #pragma unroll
        for (int i = 0; i < 8; ++i)
            res[i] = g * MbF[row * 264 + c0 + j * 8 + i] * rl + bf2f((unsigned short)xv[i]);
        *(float4*)&out[o + j * 8]     = *(float4*)&res[0];
        *(float4*)&out[o + j * 8 + 4] = *(float4*)&res[4];
    }
}

// ---------------- host launch ----------------
// Workspace (~20 MB): 0 q8 4MB | 4M k8 4MB | 8M v8 4MB | 12M x_b bf16 8MB
// 3 launches: gemm_bias (fused cast + W-transpose), gemm_qkv (fused pack + W-transpose), flash_attn.

extern "C" void kernel_launch(void* const* d_in, const int* in_sizes, int n_in,
                              void* d_out, int out_size, void* d_ws, size_t ws_size,
                              hipStream_t stream)
{
    const float* inp   = (const float*)d_in[0];
    const float* Wp    = (const float*)d_in[1];
    const float* bp    = (const float*)d_in[2];
    const float* Wq    = (const float*)d_in[3];
    const float* bq    = (const float*)d_in[4];
    const float* Wk    = (const float*)d_in[5];
    const float* bk    = (const float*)d_in[6];
    const float* Wv    = (const float*)d_in[7];
    const float* bv    = (const float*)d_in[8];
    const float* gamma = (const float*)d_in[9];
    float* out = (float*)d_out;

    char* ws = (char*)d_ws;
    unsigned char*  q8    = (unsigned char*)(ws + 0);
    unsigned char*  k8    = (unsigned char*)(ws + 4194304);
    unsigned char*  v8    = (unsigned char*)(ws + 8388608);
    unsigned short* x_b   = (unsigned short*)(ws + 12582912);

    gemm_bias<<<dim3(256, 4), 256, 0, stream>>>(inp, Wp, bp, x_b, 256);
    gemm_qkv<<<dim3(256, 4, 3), 256, 0, stream>>>(x_b, Wq, Wk, Wv, bq, bk, bv,
                                                  q8, k8, v8, 256);
    flash_attn<<<256, 512, 0, stream>>>(q8, k8, v8, x_b, gamma, out);
}